// Round 2
// baseline (662.213 us; speedup 1.0000x reference)
//
#include <hip/hip_runtime.h>

typedef unsigned short ushort_t;
typedef __attribute__((ext_vector_type(8))) __bf16 bf16x8;
typedef __attribute__((ext_vector_type(4))) float floatx4;

#define TOKS 100352   // 32*56*56

// ---------- helpers ----------
__device__ __forceinline__ ushort_t f2bf(float f) {
    union { float f; unsigned u; } a; a.f = f;
    unsigned r = a.u + 0x7fffu + ((a.u >> 16) & 1u);   // RNE
    return (ushort_t)(r >> 16);
}
__device__ __forceinline__ float bf2f(ushort_t u) {
    union { unsigned v; float f; } a; a.v = ((unsigned)u) << 16; return a.f;
}

__device__ __forceinline__ void async16(const void* g, void* l) {
    __builtin_amdgcn_global_load_lds(
        (const __attribute__((address_space(1))) unsigned int*)g,
        (__attribute__((address_space(3))) unsigned int*)l,
        16, 0, 0);
}

// window-layout token -> original token (shift +3 both axes). Bijection.
__device__ __forceinline__ int win_to_orig(int t) {
    int b = t / 3136, rr = t - b * 3136;
    int w_ = rr / 49, pos = rr - w_ * 49;
    int wi = w_ >> 3, wj = w_ & 7;
    int ti = pos / 7, tj = pos - ti * 7;
    int h = wi * 7 + ti + 3; if (h >= 56) h -= 56;
    int w = wj * 7 + tj + 3; if (w >= 56) w -= 56;
    return b * 3136 + h * 56 + w;
}

// ---------- weight convert + bias table in MFMA C-fragment layout ----------
// bmF layout (f32): idx = ((wimg*8+head)*4096) + t*256 + lane*4 + r
//   t = mi*4+nj (16x16 tile), lane = quad*16+l15, r = acc reg
//   value = rpb[rel_idx[ii*49+jj]*8+head] + amask[wimg*2401+ii*49+jj]  (ii,jj < 49)
//         = -1e30  (pad)                    -- 8.4 MB, L2/L3-resident
// Also: wq rows <256 pre-scaled by 32^-0.5; qb2 = scaled qkv bias copy.
__global__ void convert_kernel(const float* __restrict__ qkv_w, const float* __restrict__ proj_w,
                               const float* __restrict__ fc1_w, const float* __restrict__ fc2_w,
                               const float* __restrict__ rpb, const int* __restrict__ rel_idx,
                               const float* __restrict__ amask, const float* __restrict__ qkv_b,
                               ushort_t* __restrict__ wq, ushort_t* __restrict__ wp,
                               ushort_t* __restrict__ w1, ushort_t* __restrict__ w2,
                               float* __restrict__ bmF, float* __restrict__ qb2) {
    const float scale = 0.17677669529663687f;   // 32^-0.5
    int i = blockIdx.x * 256 + threadIdx.x;     // grid covers 2,097,152
    if (i < 196608) { float v = qkv_w[i]; wq[i] = f2bf(i < 65536 ? v * scale : v); }
    if (i < 65536)  wp[i] = f2bf(proj_w[i]);
    if (i < 262144) { w1[i] = f2bf(fc1_w[i]); w2[i] = f2bf(fc2_w[i]); }
    if (i < 768)    qb2[i] = qkv_b[i] * (i < 256 ? scale : 1.f);
    if (i < 2097152) {
        int r = i & 3, lane = (i >> 2) & 63, t = (i >> 8) & 15, wh = i >> 12;
        int head = wh & 7, wimg = wh >> 3;
        int mi = t >> 2, nj = t & 3;
        int quad = lane >> 4, l15 = lane & 15;
        int ii = mi * 16 + quad * 4 + r, jj = nj * 16 + l15;
        float val = -1e30f;
        if (ii < 49 && jj < 49)
            val = rpb[rel_idx[ii * 49 + jj] * 8 + head] + amask[wimg * 2401 + ii * 49 + jj];
        bmF[i] = val;
    }
}

// ---------- LN1 fused with shift + window-partition gather ----------
__global__ __launch_bounds__(256) void ln_kernel(const float* __restrict__ xin,
                                                 const float* __restrict__ gw,
                                                 const float* __restrict__ gb,
                                                 ushort_t* __restrict__ outb) {
    const int wid = threadIdx.x >> 6, lane = threadIdx.x & 63;
    const int t_out = blockIdx.x * 4 + wid;
    const int t_in = win_to_orig(t_out);
    const float4* src = (const float4*)(xin + (long)t_in * 256);
    float4 v = src[lane];
    float s  = v.x + v.y + v.z + v.w;
    float s2 = v.x*v.x + v.y*v.y + v.z*v.z + v.w*v.w;
    #pragma unroll
    for (int d = 32; d >= 1; d >>= 1) { s += __shfl_xor(s, d, 64); s2 += __shfl_xor(s2, d, 64); }
    float mu  = s * 0.00390625f;
    float var = s2 * 0.00390625f - mu * mu;
    float ry  = rsqrtf(var + 1e-5f);
    float4 w4 = ((const float4*)gw)[lane], b4 = ((const float4*)gb)[lane];
    unsigned long long p =
          (unsigned long long)f2bf((v.x - mu) * ry * w4.x + b4.x)
        | ((unsigned long long)f2bf((v.y - mu) * ry * w4.y + b4.y) << 16)
        | ((unsigned long long)f2bf((v.z - mu) * ry * w4.z + b4.z) << 32)
        | ((unsigned long long)f2bf((v.w - mu) * ry * w4.w + b4.w) << 48);
    ((unsigned long long*)(outb + (long)t_out * 256))[lane] = p;
}

// ---------- 128x128 MFMA GEMM, XCD-swizzled 1-D grid ----------
// grid.x = RT*CT, RT multiple of 8. v=blockIdx.x: xcd=v&7, col=(v>>3)%CT,
// band=(v>>3)/CT, row=band*8+xcd  -> all CT col-tiles of a band co-run on one XCD,
// so the A row-band is fetched from HBM once and re-read from that XCD's L2.
// MODE 0: out bf16 = acc + bias                                  (QKV)
// MODE 2: out bf16 = gelu(acc + bias)                            (fc1)
// MODE 4: out fp32 scatter win->orig = acc + bias + x1w[row]     (fc2, final)
template <int MODE, int N_LD, int KD, int CT>
__global__ __launch_bounds__(256, 2) void gemm_kernel(const ushort_t* __restrict__ A,
                                                      const ushort_t* __restrict__ Bw,
                                                      const float* __restrict__ bias,
                                                      void* __restrict__ outp,
                                                      const ushort_t* __restrict__ x1w,
                                                      int rowOff) {
    __shared__ __align__(16) ushort_t As[128 * 32];
    __shared__ __align__(16) ushort_t Bs[128 * 32];
    const int tid = threadIdx.x;
    const int lane = tid & 63;
    const int wid = tid >> 6;
    const int wm = wid & 1, wn = wid >> 1;
    const int l15 = lane & 15, quad = lane >> 4;
    const int v = blockIdx.x;
    const int j = v >> 3;
    const long tileM = (long)((j / CT) * 8 + (v & 7)) * 128;
    const long tileN = (long)(j % CT) * 128;

    floatx4 acc[4][4];
    #pragma unroll
    for (int i = 0; i < 4; i++)
        #pragma unroll
        for (int jj = 0; jj < 4; jj++) acc[i][jj] = {0.f, 0.f, 0.f, 0.f};

    const int o1 = tid * 16;
    const int r1 = o1 >> 6, c1 = (o1 & 63) >> 1;
    const ushort_t* Ar1 = A + (tileM + r1) * KD + c1;
    const ushort_t* Ar2 = A + (tileM + r1 + 64) * KD + c1;
    const ushort_t* Br1 = Bw + (tileN + r1) * KD + c1;
    const ushort_t* Br2 = Bw + (tileN + r1 + 64) * KD + c1;
    ushort_t* Ad1 = &As[o1 >> 1];
    ushort_t* Ad2 = &As[(o1 >> 1) + 2048];
    ushort_t* Bd1 = &Bs[o1 >> 1];
    ushort_t* Bd2 = &Bs[(o1 >> 1) + 2048];

    for (int k0 = 0; k0 < KD; k0 += 32) {
        async16(Ar1 + k0, Ad1);
        async16(Ar2 + k0, Ad2);
        async16(Br1 + k0, Bd1);
        async16(Br2 + k0, Bd2);
        __syncthreads();
        bf16x8 af[4], bfr[4];
        #pragma unroll
        for (int mi = 0; mi < 4; mi++)
            af[mi] = *(const bf16x8*)&As[(wm * 64 + mi * 16 + l15) * 32 + quad * 8];
        #pragma unroll
        for (int nj = 0; nj < 4; nj++)
            bfr[nj] = *(const bf16x8*)&Bs[(wn * 64 + nj * 16 + l15) * 32 + quad * 8];
        #pragma unroll
        for (int mi = 0; mi < 4; mi++)
            #pragma unroll
            for (int nj = 0; nj < 4; nj++)
                acc[mi][nj] = __builtin_amdgcn_mfma_f32_16x16x32_bf16(af[mi], bfr[nj], acc[mi][nj], 0, 0, 0);
        __syncthreads();
    }

    #pragma unroll
    for (int mi = 0; mi < 4; mi++)
      #pragma unroll
      for (int nj = 0; nj < 4; nj++)
        #pragma unroll
        for (int r = 0; r < 4; r++) {
            long row = tileM + wm * 64 + mi * 16 + quad * 4 + r;
            long col = tileN + wn * 64 + nj * 16 + l15;
            float val = acc[mi][nj][r] + bias[col];
            if (MODE == 0) {
                ((ushort_t*)outp)[row * N_LD + col] = f2bf(val);
            } else if (MODE == 2) {
                float g = 0.5f * val * (1.f + erff(val * 0.70710678118654752f));
                ((ushort_t*)outp)[row * N_LD + col] = f2bf(g);
            } else {  // MODE 4
                float res = bf2f(x1w[row * 256 + col]);
                int orig = win_to_orig((int)row + rowOff);
                ((float*)outp)[(long)orig * 256 + col] = val + res;
            }
        }
}

// ---------- proj GEMM + residual + LN2 (barrier-free GEMM, direct-global frags) ----------
// B (proj weight, 128 KB) is L2-resident and shared by all blocks; A tile (32 KB) has
// only 4x reuse (L1-served). So: no LDS staging, no per-K-step barriers, no vmcnt(0)
// drains, no bank conflicts. Fully-unrolled K loop of 16 B loads + MFMAs pipelines deep.
// One barrier + tiny LDS remain for the cross-wave LN reduction.
__global__ __launch_bounds__(256, 3) void proj_ln_kernel(
        const ushort_t* __restrict__ A, const ushort_t* __restrict__ Bw,
        const float* __restrict__ pb, const float* __restrict__ x_res,
        const float* __restrict__ n2w, const float* __restrict__ n2b,
        ushort_t* __restrict__ x1w, ushort_t* __restrict__ h2out) {
    __shared__ float red_s[4][64];
    __shared__ float red_q[4][64];
    const int tid = threadIdx.x, lane = tid & 63, wid = tid >> 6;
    const int l15 = lane & 15, quad = lane >> 4;
    const long tileM = (long)blockIdx.x * 64;

    floatx4 acc[4][4];
    #pragma unroll
    for (int i = 0; i < 4; i++)
        #pragma unroll
        for (int j = 0; j < 4; j++) acc[i][j] = {0.f, 0.f, 0.f, 0.f};

    // A frag rows: tileM + mi*16 + l15 ; B frag rows: wid*64 + nj*16 + l15 ; cols k0+quad*8
    const ushort_t* Ab = A + (tileM + l15) * 256 + quad * 8;
    const ushort_t* Bb = Bw + ((long)(wid * 64 + l15)) * 256 + quad * 8;

    #pragma unroll
    for (int k0 = 0; k0 < 256; k0 += 32) {
        bf16x8 af[4], bfr[4];
        #pragma unroll
        for (int mi = 0; mi < 4; mi++)
            af[mi] = *(const bf16x8*)(Ab + (mi * 16) * 256 + k0);
        #pragma unroll
        for (int nj = 0; nj < 4; nj++)
            bfr[nj] = *(const bf16x8*)(Bb + (nj * 16) * 256 + k0);
        #pragma unroll
        for (int mi = 0; mi < 4; mi++)
            #pragma unroll
            for (int nj = 0; nj < 4; nj++)
                acc[mi][nj] = __builtin_amdgcn_mfma_f32_16x16x32_bf16(af[mi], bfr[nj], acc[mi][nj], 0, 0, 0);
    }

    #pragma unroll
    for (int mi = 0; mi < 4; mi++)
      #pragma unroll
      for (int r = 0; r < 4; r++) {
        int iloc = mi * 16 + quad * 4 + r;
        int orig = win_to_orig((int)tileM + iloc);
        float s = 0.f, q = 0.f;
        #pragma unroll
        for (int nj = 0; nj < 4; nj++) {
            int col = wid * 64 + nj * 16 + l15;
            float val = acc[mi][nj][r] + pb[col] + x_res[(long)orig * 256 + col];
            x1w[(tileM + iloc) * 256 + col] = f2bf(val);
            acc[mi][nj][r] = val;
            s += val; q += val * val;
        }
        #pragma unroll
        for (int d = 1; d < 16; d <<= 1) { s += __shfl_xor(s, d, 64); q += __shfl_xor(q, d, 64); }
        if (l15 == 0) { red_s[wid][iloc] = s; red_q[wid][iloc] = q; }
      }
    __syncthreads();
    #pragma unroll
    for (int mi = 0; mi < 4; mi++)
      #pragma unroll
      for (int r = 0; r < 4; r++) {
        int iloc = mi * 16 + quad * 4 + r;
        float s = red_s[0][iloc] + red_s[1][iloc] + red_s[2][iloc] + red_s[3][iloc];
        float q = red_q[0][iloc] + red_q[1][iloc] + red_q[2][iloc] + red_q[3][iloc];
        float mu = s * 0.00390625f;
        float var = q * 0.00390625f - mu * mu;
        float rstd = rsqrtf(var + 1e-5f);
        #pragma unroll
        for (int nj = 0; nj < 4; nj++) {
            int col = wid * 64 + nj * 16 + l15;
            float val = acc[mi][nj][r];
            h2out[(tileM + iloc) * 256 + col] = f2bf((val - mu) * rstd * n2w[col] + n2b[col]);
        }
      }
}

// ---------- attention: 4 waves/block, bias pre-baked as MFMA C-init ----------
__global__ __launch_bounds__(256) void attn_kernel(const ushort_t* __restrict__ qkv,
                                                   const float* __restrict__ bmF,
                                                   ushort_t* __restrict__ attnout) {
    __shared__ __align__(16) ushort_t lds[4 * 5832];   // per wave: P[49][72] + Vt[32][72]
    const int tid = threadIdx.x, lane = tid & 63, wid = tid >> 6;
    ushort_t* Pl = &lds[wid * 5832];
    ushort_t* Vt = Pl + 49 * 72;
    const int whid = blockIdx.x * 4 + wid;             // 16384 window-heads
    const int win = whid >> 3, head = whid & 7;
    const int l15 = lane & 15, quad = lane >> 4;
    const long base = (long)win * 49 * 768;

    // bias fragments (rpb + shift-mask + pad, f32, C-frag layout) -> accumulator init
    const floatx4* bmc = (const floatx4*)bmF
                       + ((long)((win & 63) * 8 + head) * 16) * 64 + lane;
    floatx4 S[4][4];
    #pragma unroll
    for (int mi = 0; mi < 4; mi++)
        #pragma unroll
        for (int nj = 0; nj < 4; nj++)
            S[mi][nj] = bmc[(mi * 4 + nj) * 64];

    // Q (A-frag) and K (B-frag) straight from global (Q pre-scaled via wq)
    bf16x8 qf[4], kf[4];
    #pragma unroll
    for (int t4 = 0; t4 < 4; t4++) {
        int tok = t4 * 16 + l15; if (tok > 48) tok = 48;
        const ushort_t* p = qkv + base + (long)tok * 768 + head * 32 + quad * 8;
        qf[t4] = *(const bf16x8*)p;
        kf[t4] = *(const bf16x8*)(p + 256);
    }

    // V global loads issued early (written to LDS after MFMA)
    const int jl = lane;
    const int jc = jl < 49 ? jl : 48;
    const uint4* vsrc = (const uint4*)(qkv + base + (long)jc * 768 + 512 + head * 32);
    uint4 vz; vz.x = vz.y = vz.z = vz.w = 0u;
    uint4 vv[4];
    #pragma unroll
    for (int q4 = 0; q4 < 4; q4++) vv[q4] = (jl < 49) ? vsrc[q4] : vz;

    // QK^T with bias/mask/pad already in the accumulator
    #pragma unroll
    for (int mi = 0; mi < 4; mi++)
        #pragma unroll
        for (int nj = 0; nj < 4; nj++)
            S[mi][nj] = __builtin_amdgcn_mfma_f32_16x16x32_bf16(qf[mi], kf[nj], S[mi][nj], 0, 0, 0);

    // stage V^T into LDS (stride 72)
    #pragma unroll
    for (int q4 = 0; q4 < 4; q4++) {
        int db = q4 * 8;
        uint4 v4 = vv[q4];
        Vt[(db+0)*72 + jl] = (ushort_t)v4.x;  Vt[(db+1)*72 + jl] = (ushort_t)(v4.x >> 16);
        Vt[(db+2)*72 + jl] = (ushort_t)v4.y;  Vt[(db+3)*72 + jl] = (ushort_t)(v4.y >> 16);
        Vt[(db+4)*72 + jl] = (ushort_t)v4.z;  Vt[(db+5)*72 + jl] = (ushort_t)(v4.z >> 16);
        Vt[(db+6)*72 + jl] = (ushort_t)v4.w;  Vt[(db+7)*72 + jl] = (ushort_t)(v4.w >> 16);
    }

    // row softmax (unnormalized into P; 1/sum folded into output epilogue)
    float rinv[4][4];
    #pragma unroll
    for (int mi = 0; mi < 4; mi++)
      #pragma unroll
      for (int r = 0; r < 4; r++) {
          float m = fmaxf(fmaxf(S[mi][0][r], S[mi][1][r]), fmaxf(S[mi][2][r], S[mi][3][r]));
          #pragma unroll
          for (int d = 1; d < 16; d <<= 1) m = fmaxf(m, __shfl_xor(m, d, 64));
          float e[4], sum = 0.f;
          #pragma unroll
          for (int nj = 0; nj < 4; nj++) { e[nj] = __expf(S[mi][nj][r] - m); sum += e[nj]; }
          #pragma unroll
          for (int d = 1; d < 16; d <<= 1) sum += __shfl_xor(sum, d, 64);
          rinv[mi][r] = 1.f / sum;
          int i = mi * 16 + quad * 4 + r;
          if (i < 49) {
              #pragma unroll
              for (int nj = 0; nj < 4; nj++) Pl[i * 72 + (nj * 16 + l15)] = f2bf(e[nj]);
          }
      }

    // no __syncthreads: Pl/Vt are wave-private; same-wave LDS ordering via lgkmcnt

    floatx4 O[4][2];
    #pragma unroll
    for (int mi = 0; mi < 4; mi++) { O[mi][0] = {0.f,0.f,0.f,0.f}; O[mi][1] = {0.f,0.f,0.f,0.f}; }
    #pragma unroll
    for (int kc = 0; kc < 2; kc++) {
        bf16x8 pf[4], vf[2];
        #pragma unroll
        for (int mi = 0; mi < 4; mi++) {
            int pr = mi * 16 + l15; if (pr > 48) pr = 48;   // rows >=49 unwritten; clamp
            pf[mi] = *(const bf16x8*)&Pl[pr * 72 + kc * 32 + quad * 8];
        }
        #pragma unroll
        for (int n2 = 0; n2 < 2; n2++)
            vf[n2] = *(const bf16x8*)&Vt[(n2 * 16 + l15) * 72 + kc * 32 + quad * 8];
        #pragma unroll
        for (int mi = 0; mi < 4; mi++)
            #pragma unroll
            for (int n2 = 0; n2 < 2; n2++)
                O[mi][n2] = __builtin_amdgcn_mfma_f32_16x16x32_bf16(pf[mi], vf[n2], O[mi][n2], 0, 0, 0);
    }

    #pragma unroll
    for (int mi = 0; mi < 4; mi++)
      #pragma unroll
      for (int n2 = 0; n2 < 2; n2++)
        #pragma unroll
        for (int r = 0; r < 4; r++) {
            int i = mi * 16 + quad * 4 + r;
            if (i < 49) {
                long orow = ((long)win * 49 + i) * 256 + head * 32 + n2 * 16 + l15;
                attnout[orow] = f2bf(O[mi][n2][r] * rinv[mi][r]);
            }
        }
}

// ---------- launcher ----------
extern "C" void kernel_launch(void* const* d_in, const int* in_sizes, int n_in,
                              void* d_out, int out_size, void* d_ws, size_t ws_size,
                              hipStream_t stream) {
    const float* x      = (const float*)d_in[0];
    const float* n1w    = (const float*)d_in[1];
    const float* n1b    = (const float*)d_in[2];
    const float* qkv_w  = (const float*)d_in[3];
    const float* qkv_b  = (const float*)d_in[4];
    const float* rpb    = (const float*)d_in[5];
    const float* proj_w = (const float*)d_in[6];
    const float* proj_b = (const float*)d_in[7];
    const float* n2w    = (const float*)d_in[8];
    const float* n2b    = (const float*)d_in[9];
    const float* fc1_w  = (const float*)d_in[10];
    const float* fc1_b  = (const float*)d_in[11];
    const float* fc2_w  = (const float*)d_in[12];
    const float* fc2_b  = (const float*)d_in[13];
    const int*   rel_idx= (const int*)d_in[14];
    const float* amask  = (const float*)d_in[15];

    // ws layout (peak 207,093,760 B):
    char* ws = (char*)d_ws;
    ushort_t* wq   = (ushort_t*)(ws + 0);          //  393,216 B
    ushort_t* wp   = (ushort_t*)(ws + 393216);     //  131,072 B
    ushort_t* w1   = (ushort_t*)(ws + 524288);     //  524,288 B
    ushort_t* w2   = (ushort_t*)(ws + 1048576);    //  524,288 B
    ushort_t* hwin = (ushort_t*)(ws + 1572864);    // 51,380,224 B (LN1 out; reused attn_out; later h3)
    ushort_t* qkvb = (ushort_t*)(ws + 52953088);   // 154,140,672 B (qkv; reused h2 + x1w)
    ushort_t* h2   = (ushort_t*)(ws + 104333312);  // 51,380,224 B
    ushort_t* x1w  = (ushort_t*)(ws + 155713536);  // 51,380,224 B
    ushort_t* h3   = hwin;                         // 102,760,448 B per half (ends at h2)
    // bmF (f32 frag-layout bias table, 8,388,608 B) + qb2 (3,072 B) live in d_out
    // scratch — dead after attn/qkv, before fc2 writes d_out
    float* bmF = (float*)d_out;
    float* qb2 = (float*)((char*)d_out + 8388608);

    convert_kernel<<<8192, 256, 0, stream>>>(qkv_w, proj_w, fc1_w, fc2_w, rpb, rel_idx,
                                             amask, qkv_b, wq, wp, w1, w2, bmF, qb2);
    ln_kernel<<<TOKS / 4, 256, 0, stream>>>(x, n1w, n1b, hwin);
    // QKV: RT=784, CT=6  (bias = scaled copy qb2)
    gemm_kernel<0, 768, 256, 6><<<4704, 256, 0, stream>>>(hwin, wq, qb2, qkvb, nullptr, 0);
    attn_kernel<<<4096, 256, 0, stream>>>(qkvb, bmF, hwin);
    proj_ln_kernel<<<1568, 256, 0, stream>>>(hwin, wp, proj_b, x, n2w, n2b, x1w, h2);
    for (int c = 0; c < 2; c++) {
        // fc1: RT=392, CT=8
        gemm_kernel<2, 1024, 256, 8><<<3136, 256, 0, stream>>>(
            h2 + (long)c * 50176 * 256, w1, fc1_b, h3, nullptr, 0);
        // fc2: RT=392, CT=2
        gemm_kernel<4, 256, 1024, 2><<<784, 256, 0, stream>>>(
            h3, w2, fc2_b, (float*)d_out, x1w + (long)c * 50176 * 256, c * 50176);
    }
    (void)in_sizes; (void)n_in; (void)out_size; (void)ws_size;
}

// Round 3
// 623.576 us; speedup vs baseline: 1.0620x; 1.0620x over previous
//
#include <hip/hip_runtime.h>

typedef unsigned short ushort_t;
typedef __attribute__((ext_vector_type(8))) __bf16 bf16x8;
typedef __attribute__((ext_vector_type(4))) float floatx4;

#define TOKS 100352   // 32*56*56

// ---------- helpers ----------
__device__ __forceinline__ ushort_t f2bf(float f) {
    union { float f; unsigned u; } a; a.f = f;
    unsigned r = a.u + 0x7fffu + ((a.u >> 16) & 1u);   // RNE
    return (ushort_t)(r >> 16);
}
__device__ __forceinline__ float bf2f(ushort_t u) {
    union { unsigned v; float f; } a; a.v = ((unsigned)u) << 16; return a.f;
}

__device__ __forceinline__ void async16(const void* g, void* l) {
    __builtin_amdgcn_global_load_lds(
        (const __attribute__((address_space(1))) unsigned int*)g,
        (__attribute__((address_space(3))) unsigned int*)l,
        16, 0, 0);
}

// window-layout token -> original token (shift +3 both axes). Bijection.
__device__ __forceinline__ int win_to_orig(int t) {
    int b = t / 3136, rr = t - b * 3136;
    int w_ = rr / 49, pos = rr - w_ * 49;
    int wi = w_ >> 3, wj = w_ & 7;
    int ti = pos / 7, tj = pos - ti * 7;
    int h = wi * 7 + ti + 3; if (h >= 56) h -= 56;
    int w = wj * 7 + tj + 3; if (w >= 56) w -= 56;
    return b * 3136 + h * 56 + w;
}

// ---------- weight convert + bias table in MFMA C-fragment layout ----------
__global__ void convert_kernel(const float* __restrict__ qkv_w, const float* __restrict__ proj_w,
                               const float* __restrict__ fc1_w, const float* __restrict__ fc2_w,
                               const float* __restrict__ rpb, const int* __restrict__ rel_idx,
                               const float* __restrict__ amask, const float* __restrict__ qkv_b,
                               ushort_t* __restrict__ wq, ushort_t* __restrict__ wp,
                               ushort_t* __restrict__ w1, ushort_t* __restrict__ w2,
                               float* __restrict__ bmF, float* __restrict__ qb2) {
    const float scale = 0.17677669529663687f;   // 32^-0.5
    int i = blockIdx.x * 256 + threadIdx.x;     // grid covers 2,097,152
    if (i < 196608) { float v = qkv_w[i]; wq[i] = f2bf(i < 65536 ? v * scale : v); }
    if (i < 65536)  wp[i] = f2bf(proj_w[i]);
    if (i < 262144) { w1[i] = f2bf(fc1_w[i]); w2[i] = f2bf(fc2_w[i]); }
    if (i < 768)    qb2[i] = qkv_b[i] * (i < 256 ? scale : 1.f);
    if (i < 2097152) {
        int r = i & 3, lane = (i >> 2) & 63, t = (i >> 8) & 15, wh = i >> 12;
        int head = wh & 7, wimg = wh >> 3;
        int mi = t >> 2, nj = t & 3;
        int quad = lane >> 4, l15 = lane & 15;
        int ii = mi * 16 + quad * 4 + r, jj = nj * 16 + l15;
        float val = -1e30f;
        if (ii < 49 && jj < 49)
            val = rpb[rel_idx[ii * 49 + jj] * 8 + head] + amask[wimg * 2401 + ii * 49 + jj];
        bmF[i] = val;
    }
}

// ---------- LN1 fused with shift + window-partition gather ----------
__global__ __launch_bounds__(256) void ln_kernel(const float* __restrict__ xin,
                                                 const float* __restrict__ gw,
                                                 const float* __restrict__ gb,
                                                 ushort_t* __restrict__ outb) {
    const int wid = threadIdx.x >> 6, lane = threadIdx.x & 63;
    const int t_out = blockIdx.x * 4 + wid;
    const int t_in = win_to_orig(t_out);
    const float4* src = (const float4*)(xin + (long)t_in * 256);
    float4 v = src[lane];
    float s  = v.x + v.y + v.z + v.w;
    float s2 = v.x*v.x + v.y*v.y + v.z*v.z + v.w*v.w;
    #pragma unroll
    for (int d = 32; d >= 1; d >>= 1) { s += __shfl_xor(s, d, 64); s2 += __shfl_xor(s2, d, 64); }
    float mu  = s * 0.00390625f;
    float var = s2 * 0.00390625f - mu * mu;
    float ry  = rsqrtf(var + 1e-5f);
    float4 w4 = ((const float4*)gw)[lane], b4 = ((const float4*)gb)[lane];
    unsigned long long p =
          (unsigned long long)f2bf((v.x - mu) * ry * w4.x + b4.x)
        | ((unsigned long long)f2bf((v.y - mu) * ry * w4.y + b4.y) << 16)
        | ((unsigned long long)f2bf((v.z - mu) * ry * w4.z + b4.z) << 32)
        | ((unsigned long long)f2bf((v.w - mu) * ry * w4.w + b4.w) << 48);
    ((unsigned long long*)(outb + (long)t_out * 256))[lane] = p;
}

// ---------- 128x128 MFMA GEMM, XCD-swizzled, double-buffered counted-vmcnt ----------
// Per K-step: issue next tile's global_load_lds into buf^1, then wait vmcnt(4)
// (cur tile landed; next stays in flight across the barrier), raw s_barrier,
// compute, sched_barrier+raw s_barrier. Memory pipe never drains in the loop.
// MODE 0: out bf16 = acc + bias                                  (QKV)
// MODE 2: out bf16 = gelu(acc + bias)                            (fc1)
// MODE 4: out fp32 scatter win->orig = acc + bias + x1w[row]     (fc2, final)
template <int MODE, int N_LD, int KD, int CT>
__global__ __launch_bounds__(256, 2) void gemm_kernel(const ushort_t* __restrict__ A,
                                                      const ushort_t* __restrict__ Bw,
                                                      const float* __restrict__ bias,
                                                      void* __restrict__ outp,
                                                      const ushort_t* __restrict__ x1w,
                                                      int rowOff) {
    __shared__ __align__(16) ushort_t As[2][128 * 32];
    __shared__ __align__(16) ushort_t Bs[2][128 * 32];
    const int tid = threadIdx.x;
    const int lane = tid & 63;
    const int wid = tid >> 6;
    const int wm = wid & 1, wn = wid >> 1;
    const int l15 = lane & 15, quad = lane >> 4;
    const int v = blockIdx.x;
    const int j = v >> 3;
    const long tileM = (long)((j / CT) * 8 + (v & 7)) * 128;
    const long tileN = (long)(j % CT) * 128;

    floatx4 acc[4][4];
    #pragma unroll
    for (int i = 0; i < 4; i++)
        #pragma unroll
        for (int jj = 0; jj < 4; jj++) acc[i][jj] = {0.f, 0.f, 0.f, 0.f};

    const int o1 = tid * 16;
    const int r1 = o1 >> 6, c1 = (o1 & 63) >> 1;
    const int lo = o1 >> 1;
    const ushort_t* Ar1 = A + (tileM + r1) * KD + c1;
    const ushort_t* Ar2 = A + (tileM + r1 + 64) * KD + c1;
    const ushort_t* Br1 = Bw + (tileN + r1) * KD + c1;
    const ushort_t* Br2 = Bw + (tileN + r1 + 64) * KD + c1;

    // prologue: stage tile 0 into buf 0
    async16(Ar1, &As[0][lo]);
    async16(Ar2, &As[0][lo + 2048]);
    async16(Br1, &Bs[0][lo]);
    async16(Br2, &Bs[0][lo + 2048]);

    #pragma unroll
    for (int it = 0; it < KD / 32; ++it) {
        const int buf = it & 1, nbuf = buf ^ 1;
        const int k0 = it * 32;
        if (it + 1 < KD / 32) {
            async16(Ar1 + k0 + 32, &As[nbuf][lo]);
            async16(Ar2 + k0 + 32, &As[nbuf][lo + 2048]);
            async16(Br1 + k0 + 32, &Bs[nbuf][lo]);
            async16(Br2 + k0 + 32, &Bs[nbuf][lo + 2048]);
            asm volatile("s_waitcnt vmcnt(4)" ::: "memory");
        } else {
            asm volatile("s_waitcnt vmcnt(0)" ::: "memory");
        }
        __builtin_amdgcn_s_barrier();
        bf16x8 af[4], bfr[4];
        #pragma unroll
        for (int mi = 0; mi < 4; mi++)
            af[mi] = *(const bf16x8*)&As[buf][(wm * 64 + mi * 16 + l15) * 32 + quad * 8];
        #pragma unroll
        for (int nj = 0; nj < 4; nj++)
            bfr[nj] = *(const bf16x8*)&Bs[buf][(wn * 64 + nj * 16 + l15) * 32 + quad * 8];
        #pragma unroll
        for (int mi = 0; mi < 4; mi++)
            #pragma unroll
            for (int nj = 0; nj < 4; nj++)
                acc[mi][nj] = __builtin_amdgcn_mfma_f32_16x16x32_bf16(af[mi], bfr[nj], acc[mi][nj], 0, 0, 0);
        __builtin_amdgcn_sched_barrier(0);
        __builtin_amdgcn_s_barrier();
    }

    #pragma unroll
    for (int mi = 0; mi < 4; mi++)
      #pragma unroll
      for (int nj = 0; nj < 4; nj++)
        #pragma unroll
        for (int r = 0; r < 4; r++) {
            long row = tileM + wm * 64 + mi * 16 + quad * 4 + r;
            long col = tileN + wn * 64 + nj * 16 + l15;
            float val = acc[mi][nj][r] + bias[col];
            if (MODE == 0) {
                ((ushort_t*)outp)[row * N_LD + col] = f2bf(val);
            } else if (MODE == 2) {
                float g = 0.5f * val * (1.f + erff(val * 0.70710678118654752f));
                ((ushort_t*)outp)[row * N_LD + col] = f2bf(g);
            } else {  // MODE 4
                float res = bf2f(x1w[row * 256 + col]);
                int orig = win_to_orig((int)row + rowOff);
                ((float*)outp)[(long)orig * 256 + col] = val + res;
            }
        }
}

// ---------- proj GEMM + residual + LN2 (LDS-staged, double-buffered counted-vmcnt) ----------
__global__ __launch_bounds__(256, 2) void proj_ln_kernel(
        const ushort_t* __restrict__ A, const ushort_t* __restrict__ Bw,
        const float* __restrict__ pb, const float* __restrict__ x_res,
        const float* __restrict__ n2w, const float* __restrict__ n2b,
        ushort_t* __restrict__ x1w, ushort_t* __restrict__ h2out) {
    __shared__ __align__(16) ushort_t As[2][64 * 32];      // 2 x 4 KB
    __shared__ __align__(16) ushort_t Bs[2][256 * 32];     // 2 x 16 KB
    __shared__ float red_s[4][64];
    __shared__ float red_q[4][64];
    const int tid = threadIdx.x, lane = tid & 63, wid = tid >> 6;
    const int l15 = lane & 15, quad = lane >> 4;
    const long tileM = (long)blockIdx.x * 64;

    floatx4 acc[4][4];
    #pragma unroll
    for (int i = 0; i < 4; i++)
        #pragma unroll
        for (int j = 0; j < 4; j++) acc[i][j] = {0.f, 0.f, 0.f, 0.f};

    const int oA = tid * 16;
    const int rA = oA >> 6, cA = (oA & 63) >> 1;
    const ushort_t* Ap = A + (tileM + rA) * 256 + cA;

    // prologue: stage K-step 0 into buf 0
    async16(Ap, &As[0][oA >> 1]);
    #pragma unroll
    for (int ch = 0; ch < 4; ch++) {
        int o = ch * 4096 + oA;
        async16(Bw + (o >> 6) * 256 + ((o & 63) >> 1), &Bs[0][o >> 1]);
    }

    #pragma unroll
    for (int it = 0; it < 8; ++it) {
        const int buf = it & 1, nbuf = buf ^ 1;
        const int k0 = it * 32;
        if (it + 1 < 8) {
            async16(Ap + k0 + 32, &As[nbuf][oA >> 1]);
            #pragma unroll
            for (int ch = 0; ch < 4; ch++) {
                int o = ch * 4096 + oA;
                async16(Bw + (o >> 6) * 256 + ((o & 63) >> 1) + k0 + 32, &Bs[nbuf][o >> 1]);
            }
            asm volatile("s_waitcnt vmcnt(5)" ::: "memory");
        } else {
            asm volatile("s_waitcnt vmcnt(0)" ::: "memory");
        }
        __builtin_amdgcn_s_barrier();
        bf16x8 af[4], bfr[4];
        #pragma unroll
        for (int mi = 0; mi < 4; mi++)
            af[mi] = *(const bf16x8*)&As[buf][(mi * 16 + l15) * 32 + quad * 8];
        #pragma unroll
        for (int nj = 0; nj < 4; nj++)
            bfr[nj] = *(const bf16x8*)&Bs[buf][(wid * 64 + nj * 16 + l15) * 32 + quad * 8];
        #pragma unroll
        for (int mi = 0; mi < 4; mi++)
            #pragma unroll
            for (int nj = 0; nj < 4; nj++)
                acc[mi][nj] = __builtin_amdgcn_mfma_f32_16x16x32_bf16(af[mi], bfr[nj], acc[mi][nj], 0, 0, 0);
        __builtin_amdgcn_sched_barrier(0);
        __builtin_amdgcn_s_barrier();
    }

    #pragma unroll
    for (int mi = 0; mi < 4; mi++)
      #pragma unroll
      for (int r = 0; r < 4; r++) {
        int iloc = mi * 16 + quad * 4 + r;
        int orig = win_to_orig((int)tileM + iloc);
        float s = 0.f, q = 0.f;
        #pragma unroll
        for (int nj = 0; nj < 4; nj++) {
            int col = wid * 64 + nj * 16 + l15;
            float val = acc[mi][nj][r] + pb[col] + x_res[(long)orig * 256 + col];
            x1w[(tileM + iloc) * 256 + col] = f2bf(val);
            acc[mi][nj][r] = val;
            s += val; q += val * val;
        }
        #pragma unroll
        for (int d = 1; d < 16; d <<= 1) { s += __shfl_xor(s, d, 64); q += __shfl_xor(q, d, 64); }
        if (l15 == 0) { red_s[wid][iloc] = s; red_q[wid][iloc] = q; }
      }
    __syncthreads();
    #pragma unroll
    for (int mi = 0; mi < 4; mi++)
      #pragma unroll
      for (int r = 0; r < 4; r++) {
        int iloc = mi * 16 + quad * 4 + r;
        float s = red_s[0][iloc] + red_s[1][iloc] + red_s[2][iloc] + red_s[3][iloc];
        float q = red_q[0][iloc] + red_q[1][iloc] + red_q[2][iloc] + red_q[3][iloc];
        float mu = s * 0.00390625f;
        float var = q * 0.00390625f - mu * mu;
        float rstd = rsqrtf(var + 1e-5f);
        #pragma unroll
        for (int nj = 0; nj < 4; nj++) {
            int col = wid * 64 + nj * 16 + l15;
            float val = acc[mi][nj][r];
            h2out[(tileM + iloc) * 256 + col] = f2bf((val - mu) * rstd * n2w[col] + n2b[col]);
        }
      }
}

// ---------- attention: 4 waves/block, bias pre-baked as MFMA C-init ----------
__global__ __launch_bounds__(256) void attn_kernel(const ushort_t* __restrict__ qkv,
                                                   const float* __restrict__ bmF,
                                                   ushort_t* __restrict__ attnout) {
    __shared__ __align__(16) ushort_t lds[4 * 5832];   // per wave: P[49][72] + Vt[32][72]
    const int tid = threadIdx.x, lane = tid & 63, wid = tid >> 6;
    ushort_t* Pl = &lds[wid * 5832];
    ushort_t* Vt = Pl + 49 * 72;
    const int whid = blockIdx.x * 4 + wid;             // 16384 window-heads
    const int win = whid >> 3, head = whid & 7;
    const int l15 = lane & 15, quad = lane >> 4;
    const long base = (long)win * 49 * 768;

    // bias fragments (rpb + shift-mask + pad, f32, C-frag layout) -> accumulator init
    const floatx4* bmc = (const floatx4*)bmF
                       + ((long)((win & 63) * 8 + head) * 16) * 64 + lane;
    floatx4 S[4][4];
    #pragma unroll
    for (int mi = 0; mi < 4; mi++)
        #pragma unroll
        for (int nj = 0; nj < 4; nj++)
            S[mi][nj] = bmc[(mi * 4 + nj) * 64];

    // Q (A-frag) and K (B-frag) straight from global (Q pre-scaled via wq)
    bf16x8 qf[4], kf[4];
    #pragma unroll
    for (int t4 = 0; t4 < 4; t4++) {
        int tok = t4 * 16 + l15; if (tok > 48) tok = 48;
        const ushort_t* p = qkv + base + (long)tok * 768 + head * 32 + quad * 8;
        qf[t4] = *(const bf16x8*)p;
        kf[t4] = *(const bf16x8*)(p + 256);
    }

    // V global loads issued early (written to LDS after MFMA)
    const int jl = lane;
    const int jc = jl < 49 ? jl : 48;
    const uint4* vsrc = (const uint4*)(qkv + base + (long)jc * 768 + 512 + head * 32);
    uint4 vz; vz.x = vz.y = vz.z = vz.w = 0u;
    uint4 vv[4];
    #pragma unroll
    for (int q4 = 0; q4 < 4; q4++) vv[q4] = (jl < 49) ? vsrc[q4] : vz;

    // QK^T with bias/mask/pad already in the accumulator
    #pragma unroll
    for (int mi = 0; mi < 4; mi++)
        #pragma unroll
        for (int nj = 0; nj < 4; nj++)
            S[mi][nj] = __builtin_amdgcn_mfma_f32_16x16x32_bf16(qf[mi], kf[nj], S[mi][nj], 0, 0, 0);

    // stage V^T into LDS (stride 72)
    #pragma unroll
    for (int q4 = 0; q4 < 4; q4++) {
        int db = q4 * 8;
        uint4 v4 = vv[q4];
        Vt[(db+0)*72 + jl] = (ushort_t)v4.x;  Vt[(db+1)*72 + jl] = (ushort_t)(v4.x >> 16);
        Vt[(db+2)*72 + jl] = (ushort_t)v4.y;  Vt[(db+3)*72 + jl] = (ushort_t)(v4.y >> 16);
        Vt[(db+4)*72 + jl] = (ushort_t)v4.z;  Vt[(db+5)*72 + jl] = (ushort_t)(v4.z >> 16);
        Vt[(db+6)*72 + jl] = (ushort_t)v4.w;  Vt[(db+7)*72 + jl] = (ushort_t)(v4.w >> 16);
    }

    // row softmax (unnormalized into P; 1/sum folded into output epilogue)
    float rinv[4][4];
    #pragma unroll
    for (int mi = 0; mi < 4; mi++)
      #pragma unroll
      for (int r = 0; r < 4; r++) {
          float m = fmaxf(fmaxf(S[mi][0][r], S[mi][1][r]), fmaxf(S[mi][2][r], S[mi][3][r]));
          #pragma unroll
          for (int d = 1; d < 16; d <<= 1) m = fmaxf(m, __shfl_xor(m, d, 64));
          float e[4], sum = 0.f;
          #pragma unroll
          for (int nj = 0; nj < 4; nj++) { e[nj] = __expf(S[mi][nj][r] - m); sum += e[nj]; }
          #pragma unroll
          for (int d = 1; d < 16; d <<= 1) sum += __shfl_xor(sum, d, 64);
          rinv[mi][r] = 1.f / sum;
          int i = mi * 16 + quad * 4 + r;
          if (i < 49) {
              #pragma unroll
              for (int nj = 0; nj < 4; nj++) Pl[i * 72 + (nj * 16 + l15)] = f2bf(e[nj]);
          }
      }

    // no __syncthreads: Pl/Vt are wave-private; same-wave LDS ordering via lgkmcnt

    floatx4 O[4][2];
    #pragma unroll
    for (int mi = 0; mi < 4; mi++) { O[mi][0] = {0.f,0.f,0.f,0.f}; O[mi][1] = {0.f,0.f,0.f,0.f}; }
    #pragma unroll
    for (int kc = 0; kc < 2; kc++) {
        bf16x8 pf[4], vf[2];
        #pragma unroll
        for (int mi = 0; mi < 4; mi++) {
            int pr = mi * 16 + l15; if (pr > 48) pr = 48;   // rows >=49 unwritten; clamp
            pf[mi] = *(const bf16x8*)&Pl[pr * 72 + kc * 32 + quad * 8];
        }
        #pragma unroll
        for (int n2 = 0; n2 < 2; n2++)
            vf[n2] = *(const bf16x8*)&Vt[(n2 * 16 + l15) * 72 + kc * 32 + quad * 8];
        #pragma unroll
        for (int mi = 0; mi < 4; mi++)
            #pragma unroll
            for (int n2 = 0; n2 < 2; n2++)
                O[mi][n2] = __builtin_amdgcn_mfma_f32_16x16x32_bf16(pf[mi], vf[n2], O[mi][n2], 0, 0, 0);
    }

    #pragma unroll
    for (int mi = 0; mi < 4; mi++)
      #pragma unroll
      for (int n2 = 0; n2 < 2; n2++)
        #pragma unroll
        for (int r = 0; r < 4; r++) {
            int i = mi * 16 + quad * 4 + r;
            if (i < 49) {
                long orow = ((long)win * 49 + i) * 256 + head * 32 + n2 * 16 + l15;
                attnout[orow] = f2bf(O[mi][n2][r] * rinv[mi][r]);
            }
        }
}

// ---------- launcher ----------
extern "C" void kernel_launch(void* const* d_in, const int* in_sizes, int n_in,
                              void* d_out, int out_size, void* d_ws, size_t ws_size,
                              hipStream_t stream) {
    const float* x      = (const float*)d_in[0];
    const float* n1w    = (const float*)d_in[1];
    const float* n1b    = (const float*)d_in[2];
    const float* qkv_w  = (const float*)d_in[3];
    const float* qkv_b  = (const float*)d_in[4];
    const float* rpb    = (const float*)d_in[5];
    const float* proj_w = (const float*)d_in[6];
    const float* proj_b = (const float*)d_in[7];
    const float* n2w    = (const float*)d_in[8];
    const float* n2b    = (const float*)d_in[9];
    const float* fc1_w  = (const float*)d_in[10];
    const float* fc1_b  = (const float*)d_in[11];
    const float* fc2_w  = (const float*)d_in[12];
    const float* fc2_b  = (const float*)d_in[13];
    const int*   rel_idx= (const int*)d_in[14];
    const float* amask  = (const float*)d_in[15];

    // ws layout (peak 207,093,760 B):
    char* ws = (char*)d_ws;
    ushort_t* wq   = (ushort_t*)(ws + 0);          //  393,216 B
    ushort_t* wp   = (ushort_t*)(ws + 393216);     //  131,072 B
    ushort_t* w1   = (ushort_t*)(ws + 524288);     //  524,288 B
    ushort_t* w2   = (ushort_t*)(ws + 1048576);    //  524,288 B
    ushort_t* hwin = (ushort_t*)(ws + 1572864);    // 51,380,224 B (LN1 out; reused attn_out; later h3)
    ushort_t* qkvb = (ushort_t*)(ws + 52953088);   // 154,140,672 B (qkv; reused h2 + x1w)
    ushort_t* h2   = (ushort_t*)(ws + 104333312);  // 51,380,224 B
    ushort_t* x1w  = (ushort_t*)(ws + 155713536);  // 51,380,224 B
    ushort_t* h3   = hwin;                         // 102,760,448 B per half (ends at h2)
    // bmF (f32 frag-layout bias table, 8,388,608 B) + qb2 (3,072 B) live in d_out
    // scratch — dead after attn/qkv, before fc2 writes d_out
    float* bmF = (float*)d_out;
    float* qb2 = (float*)((char*)d_out + 8388608);

    convert_kernel<<<8192, 256, 0, stream>>>(qkv_w, proj_w, fc1_w, fc2_w, rpb, rel_idx,
                                             amask, qkv_b, wq, wp, w1, w2, bmF, qb2);
    ln_kernel<<<TOKS / 4, 256, 0, stream>>>(x, n1w, n1b, hwin);
    // QKV: RT=784, CT=6  (bias = scaled copy qb2)
    gemm_kernel<0, 768, 256, 6><<<4704, 256, 0, stream>>>(hwin, wq, qb2, qkvb, nullptr, 0);
    attn_kernel<<<4096, 256, 0, stream>>>(qkvb, bmF, hwin);
    proj_ln_kernel<<<1568, 256, 0, stream>>>(hwin, wp, proj_b, x, n2w, n2b, x1w, h2);
    for (int c = 0; c < 2; c++) {
        // fc1: RT=392, CT=8
        gemm_kernel<2, 1024, 256, 8><<<3136, 256, 0, stream>>>(
            h2 + (long)c * 50176 * 256, w1, fc1_b, h3, nullptr, 0);
        // fc2: RT=392, CT=2
        gemm_kernel<4, 256, 1024, 2><<<784, 256, 0, stream>>>(
            h3, w2, fc2_b, (float*)d_out, x1w + (long)c * 50176 * 256, c * 50176);
    }
    (void)in_sizes; (void)n_in; (void)out_size; (void)ws_size;
}